// Round 2
// baseline (376.308 us; speedup 1.0000x reference)
//
#include <hip/hip_runtime.h>

#define OUT_F 4096   // compressed rows
#define IN_F  2048   // compressed cols
#define KLOG  4096   // logical k = 2*IN_F
#define NB    4096   // batch
typedef unsigned long long ull;
typedef ull ullx2 __attribute__((ext_vector_type(2)));

typedef __bf16 bf16x8 __attribute__((ext_vector_type(8)));
typedef short  s16x8  __attribute__((ext_vector_type(8)));
typedef float  f32x4  __attribute__((ext_vector_type(4)));
typedef float  f32x16 __attribute__((ext_vector_type(16)));

__device__ __forceinline__ unsigned short f2bf(float f) {
    unsigned int u = __float_as_uint(f);
    u += 0x7fffu + ((u >> 16) & 1u);
    return (unsigned short)(u >> 16);
}

__device__ __forceinline__ void gload_lds16(const void* g, void* l) {
    __builtin_amdgcn_global_load_lds(
        (const __attribute__((address_space(1))) unsigned int*)g,
        (__attribute__((address_space(3))) unsigned int*)l, 16, 0, 0);
}

__device__ __forceinline__ bf16x8 ldsf(const char* p) {
    return __builtin_bit_cast(bf16x8, *(const s16x8*)p);
}

#define MFMA32(a, b, c) __builtin_amdgcn_mfma_f32_32x32x16_bf16((a), (b), (c), 0, 0, 0)

// ---------- Pre-pass: [0,4096) decompress weight -> bf16 wsA; [4096,8192) input -> bf16 wsB.
__global__ __launch_bounds__(256) void prep_kernel(
    const float* __restrict__ weight, const int* __restrict__ metadata,
    const float* __restrict__ input,
    unsigned short* __restrict__ wsA, unsigned short* __restrict__ wsB)
{
    const int b = blockIdx.x;
    if (b < 4096) {
        const int g = b * 256 + threadIdx.x;
        const int r = g >> 8;
        const int c = (g & 255) * 8;
        const size_t off = (size_t)r * IN_F + c;
        const float4 w0 = *(const float4*)(weight + off);
        const float4 w1 = *(const float4*)(weight + off + 4);
        const int4   m0 = *(const int4*)(metadata + off);
        const int4   m1 = *(const int4*)(metadata + off + 4);
        ullx2 v01, v23;
        v01.x = ((ull)f2bf(w0.x) << (m0.x * 16)) | ((ull)f2bf(w0.y) << (m0.y * 16));
        v01.y = ((ull)f2bf(w0.z) << (m0.z * 16)) | ((ull)f2bf(w0.w) << (m0.w * 16));
        v23.x = ((ull)f2bf(w1.x) << (m1.x * 16)) | ((ull)f2bf(w1.y) << (m1.y * 16));
        v23.y = ((ull)f2bf(w1.z) << (m1.z * 16)) | ((ull)f2bf(w1.w) << (m1.w * 16));
        ull* dst = (ull*)(wsA + (size_t)r * KLOG + 2 * c);
        *(ullx2*)(dst)     = v01;
        *(ullx2*)(dst + 2) = v23;
    } else {
        const int g = (b - 4096) * 256 + threadIdx.x;
        const size_t off = (size_t)g * 16;
        const float4 f0 = *(const float4*)(input + off);
        const float4 f1 = *(const float4*)(input + off + 4);
        const float4 f2 = *(const float4*)(input + off + 8);
        const float4 f3 = *(const float4*)(input + off + 12);
        ullx2 v01, v23;
        v01.x =  (ull)f2bf(f0.x) | ((ull)f2bf(f0.y) << 16) | ((ull)f2bf(f0.z) << 32) | ((ull)f2bf(f0.w) << 48);
        v01.y =  (ull)f2bf(f1.x) | ((ull)f2bf(f1.y) << 16) | ((ull)f2bf(f1.z) << 32) | ((ull)f2bf(f1.w) << 48);
        v23.x =  (ull)f2bf(f2.x) | ((ull)f2bf(f2.y) << 16) | ((ull)f2bf(f2.z) << 32) | ((ull)f2bf(f2.w) << 48);
        v23.y =  (ull)f2bf(f3.x) | ((ull)f2bf(f3.y) << 16) | ((ull)f2bf(f3.z) << 32) | ((ull)f2bf(f3.w) << 48);
        ull* dst = (ull*)(wsB + off);
        *(ullx2*)(dst)     = v01;
        *(ullx2*)(dst + 2) = v23;
    }
}

// ---------- Main GEMM: 256x256 tile, 8 waves (2M x 4N), BK=32, 32x32x16 bf16 MFMA.
// Ring-4 LDS (128 KB), depth-3 prefetch, counted vmcnt(8).
// ONE barrier per K-tile (tile-end vmcnt + s_barrier + sched_barrier only).
// No explicit lgkmcnt: plain ds_reads -> compiler emits fine-grained counted lgkmcnt,
// interleaving reads with the MFMA cluster (breaks the R1 read-burst/MFMA-burst lockstep).
// Swizzle: phys 16B-chunk = logical ^ ((row>>1)&3)  (conflict-free per 8-lane phase).
__global__ __launch_bounds__(512, 2) void gemm_kernel256(
    const unsigned short* __restrict__ wsA, const unsigned short* __restrict__ wsB,
    const int* __restrict__ indices, float* __restrict__ out)
{
    // 4 ring buffers x (A 256x32 bf16 = 16 KB, B 256x32 bf16 = 16 KB) = 128 KB
    __shared__ __align__(16) char lds[4 * 32768];

    const int tid  = threadIdx.x;
    const int lane = tid & 63;
    const int wave = tid >> 6;
    const int wm   = wave >> 2;   // 0..1 : 128-row half of the M-tile
    const int wn   = wave & 3;    // 0..3 : 64-col strip of the N-tile
    const int l31  = lane & 31;
    const int h    = lane >> 5;   // k-half of fragment

    // T1: XCD-aware swizzle. 256 blocks, 8 XCDs -> XCD x gets 32 consecutive tile ids.
    const int swz = ((blockIdx.x & 7) << 5) | (blockIdx.x >> 3);
    const int r0 = (swz >> 4) << 8;   // M origin
    const int b0 = (swz & 15) << 8;   // N origin

    // ---- staging: one call covers 128 rows x 32 cols (8 KB), 16B/thread ----
    // LDS byte tid*16 -> row tid>>2, phys chunk tid&3 ; source logical chunk = phys ^ ((row>>1)&3)
    const int srow   = tid >> 2;                      // 0..127
    const int schunk = (tid & 3) ^ ((tid >> 3) & 3);  // pre-swizzled source 16B-chunk
    const unsigned short* gA = wsA + (size_t)(r0 + srow) * KLOG + schunk * 8;
    const unsigned short* gB = wsB + (size_t)(b0 + srow) * KLOG + schunk * 8;
    char* const ldsW = lds + wave * 1024;             // wave-uniform staging base

    // ---- fragment-read constants ----
    const int q = (l31 >> 1) & 3;                      // == (row>>1)&3 for all frag rows
    const unsigned x0 = (unsigned)(((0 + h) ^ q) * 16);  // k-step 0: logical chunks {0,1}
    const unsigned x1 = (unsigned)(((2 + h) ^ q) * 16);  // k-step 1: logical chunks {2,3}
    const unsigned aRow = (unsigned)((wm * 128 + l31) * 64);
    const unsigned bRow = (unsigned)((wn * 64  + l31) * 64);

    f32x16 acc[4][2];
#pragma unroll
    for (int i = 0; i < 4; ++i)
#pragma unroll
        for (int j = 0; j < 2; ++j)
#pragma unroll
            for (int e = 0; e < 16; ++e) acc[i][j][e] = 0.f;

#define STAGE_A(t_) do { \
        char* _d = ldsW + (((t_) & 3) * 32768); \
        const unsigned short* _s = gA + (t_) * 32; \
        gload_lds16(_s, _d); \
        gload_lds16(_s + (size_t)128 * KLOG, _d + 8192); } while (0)
#define STAGE_B(t_) do { \
        char* _d = ldsW + (((t_) & 3) * 32768) + 16384; \
        const unsigned short* _s = gB + (t_) * 32; \
        gload_lds16(_s, _d); \
        gload_lds16(_s + (size_t)128 * KLOG, _d + 8192); } while (0)

    // prologue: stage tiles 0,1,2 (12 loads/thread); wait oldest 4 (= tile 0)
    STAGE_A(0); STAGE_B(0);
    STAGE_A(1); STAGE_B(1);
    STAGE_A(2); STAGE_B(2);
    asm volatile("s_waitcnt vmcnt(8)" ::: "memory");
    __builtin_amdgcn_s_barrier();
    __builtin_amdgcn_sched_barrier(0);

    for (int t = 0; t < 128; ++t) {
        const unsigned bufA = (unsigned)(t & 3) * 32768u;
        const char* pA = lds + bufA + aRow;
        const char* pB = lds + bufA + 16384u + bRow;

        // issue all 12 fragment reads (ordered to feed the first MFMAs) + next-tile staging;
        // compiler interleaves with counted lgkmcnt so MFMAs start while later reads land.
        bf16x8 a00 = ldsf(pA + x0);
        bf16x8 b00 = ldsf(pB + x0);
        bf16x8 b10 = ldsf(pB + 2048 + x0);
        bf16x8 a10 = ldsf(pA + 2048 + x0);
        bf16x8 a20 = ldsf(pA + 4096 + x0);
        bf16x8 a30 = ldsf(pA + 6144 + x0);
        bf16x8 a01 = ldsf(pA + x1);
        bf16x8 b01 = ldsf(pB + x1);
        bf16x8 b11 = ldsf(pB + 2048 + x1);
        bf16x8 a11 = ldsf(pA + 2048 + x1);
        bf16x8 a21 = ldsf(pA + 4096 + x1);
        bf16x8 a31 = ldsf(pA + 6144 + x1);
        if (t < 125) { STAGE_A(t + 3); STAGE_B(t + 3); }

        __builtin_amdgcn_s_setprio(1);
        acc[0][0] = MFMA32(a00, b00, acc[0][0]);
        acc[0][1] = MFMA32(a00, b10, acc[0][1]);
        acc[1][0] = MFMA32(a10, b00, acc[1][0]);
        acc[1][1] = MFMA32(a10, b10, acc[1][1]);
        acc[2][0] = MFMA32(a20, b00, acc[2][0]);
        acc[2][1] = MFMA32(a20, b10, acc[2][1]);
        acc[3][0] = MFMA32(a30, b00, acc[3][0]);
        acc[3][1] = MFMA32(a30, b10, acc[3][1]);
        acc[0][0] = MFMA32(a01, b01, acc[0][0]);
        acc[0][1] = MFMA32(a01, b11, acc[0][1]);
        acc[1][0] = MFMA32(a11, b01, acc[1][0]);
        acc[1][1] = MFMA32(a11, b11, acc[1][1]);
        acc[2][0] = MFMA32(a21, b01, acc[2][0]);
        acc[2][1] = MFMA32(a21, b11, acc[2][1]);
        acc[3][0] = MFMA32(a31, b01, acc[3][0]);
        acc[3][1] = MFMA32(a31, b11, acc[3][1]);
        __builtin_amdgcn_s_setprio(0);

        // ---- tile end: the ONLY sync per tile. Counted vmcnt (never 0 until tail). ----
        // vmcnt(8): tiles t+2,t+3 stay in flight; tile t+1's 4 loads (per wave) have landed.
        // s_barrier: makes that true for ALL waves' staged slices before anyone reads buf[t+1]
        // and before anyone stages into buf[(t+4)&3] = buf[t&3].
        if (t < 125) {
            asm volatile("s_waitcnt vmcnt(8)" ::: "memory");
        } else if (t == 125) {
            asm volatile("s_waitcnt vmcnt(4)" ::: "memory");
        } else if (t == 126) {
            asm volatile("s_waitcnt vmcnt(0)" ::: "memory");
        }
        __builtin_amdgcn_s_barrier();
        __builtin_amdgcn_sched_barrier(0);   // nothing crosses the tile boundary
    }
#undef STAGE_A
#undef STAGE_B

    // epilogue: C/D (32x32): col = l31, row = (reg&3) + 8*(reg>>2) + 4*h  [m74/m101]
#pragma unroll
    for (int fm = 0; fm < 4; ++fm) {
#pragma unroll
        for (int reg = 0; reg < 16; ++reg) {
            const int rloc = wm * 128 + fm * 32 + (reg & 3) + 8 * (reg >> 2) + 4 * h;
            const int L = indices[r0 + rloc];
            const size_t base  = (size_t)L * NB;
            const size_t baseZ = (size_t)(L ^ 1) * NB;
#pragma unroll
            for (int fn = 0; fn < 2; ++fn) {
                const int col = b0 + wn * 64 + fn * 32 + l31;
                out[base  + col] = acc[fm][fn][reg];
                out[baseZ + col] = 0.0f;
            }
        }
    }
}

// ---------- Fallback (round-1 fused kernel) if ws is too small ----------
__global__ __launch_bounds__(256) void spmm_dt_fallback(
    const float* __restrict__ weight, const int* __restrict__ indices,
    const int* __restrict__ metadata, const float* __restrict__ input,
    float* __restrict__ out)
{
    __shared__ __align__(16) unsigned short As[128][32];
    __shared__ __align__(16) unsigned short Bs[128][32];
    const int tid = threadIdx.x, lane = tid & 63, wave = tid >> 6;
    const int wm = wave >> 1, wn = wave & 1, l15 = lane & 15, quad = lane >> 4;
    const int r0 = blockIdx.y * 128, b0 = blockIdx.x * 128;
    f32x4 acc[4][4];
#pragma unroll
    for (int i = 0; i < 4; ++i)
#pragma unroll
        for (int j = 0; j < 4; ++j) acc[i][j] = (f32x4){0.f, 0.f, 0.f, 0.f};
    const int srow = tid >> 3, sgrp = tid & 7;
    for (int kk = 0; kk < KLOG / 32; ++kk) {
        const int c0 = kk * 16, k0 = kk * 32;
#pragma unroll
        for (int s = 0; s < 4; ++s) {
            const int row = srow + s * 32;
            const size_t off = (size_t)(r0 + row) * IN_F + c0 + 2 * sgrp;
            const float2 w = *(const float2*)(weight + off);
            const int2  md = *(const int2*)(metadata + off);
            *(ull*)(&As[row][4 * sgrp]) =
                ((ull)f2bf(w.x) << (md.x * 16)) | ((ull)f2bf(w.y) << (md.y * 16));
        }
#pragma unroll
        for (int s = 0; s < 4; ++s) {
            const int row = srow + s * 32;
            const float4 f = *(const float4*)(&input[(size_t)(b0 + row) * KLOG + k0 + sgrp * 4]);
            *(ull*)(&Bs[row][sgrp * 4]) =
                 (ull)f2bf(f.x) | ((ull)f2bf(f.y) << 16) |
                ((ull)f2bf(f.z) << 32) | ((ull)f2bf(f.w) << 48);
        }
        __syncthreads();
        bf16x8 a[4], b[4];
#pragma unroll
        for (int i = 0; i < 4; ++i)
            a[i] = __builtin_bit_cast(bf16x8, *(const s16x8*)(&As[wm * 64 + i * 16 + l15][quad * 8]));
#pragma unroll
        for (int j = 0; j < 4; ++j)
            b[j] = __builtin_bit_cast(bf16x8, *(const s16x8*)(&Bs[wn * 64 + j * 16 + l15][quad * 8]));
#pragma unroll
        for (int i = 0; i < 4; ++i)
#pragma unroll
            for (int j = 0; j < 4; ++j)
                acc[i][j] = __builtin_amdgcn_mfma_f32_16x16x32_bf16(a[i], b[j], acc[i][j], 0, 0, 0);
        __syncthreads();
    }
#pragma unroll
    for (int i = 0; i < 4; ++i)
#pragma unroll
        for (int t = 0; t < 4; ++t) {
            const int r = r0 + wm * 64 + i * 16 + quad * 4 + t;
            const int L = indices[r];
            const size_t base = (size_t)L * NB, baseZ = (size_t)(L ^ 1) * NB;
#pragma unroll
            for (int j = 0; j < 4; ++j) {
                const int col = b0 + wn * 64 + j * 16 + l15;
                out[base + col] = acc[i][j][t];
                out[baseZ + col] = 0.0f;
            }
        }
}

extern "C" void kernel_launch(void* const* d_in, const int* in_sizes, int n_in,
                              void* d_out, int out_size, void* d_ws, size_t ws_size,
                              hipStream_t stream) {
    const float* weight   = (const float*)d_in[0];
    const int*   indices  = (const int*)d_in[1];
    const int*   metadata = (const int*)d_in[2];
    const float* input    = (const float*)d_in[3];
    float*       out      = (float*)d_out;

    const size_t needA = (size_t)OUT_F * KLOG * 2;  // 32 MB
    const size_t needB = (size_t)NB * KLOG * 2;     // 32 MB
    if (ws_size >= needA + needB) {
        unsigned short* wsA = (unsigned short*)d_ws;
        unsigned short* wsB = wsA + (size_t)OUT_F * KLOG;
        prep_kernel<<<dim3(8192), dim3(256), 0, stream>>>(weight, metadata, input, wsA, wsB);
        gemm_kernel256<<<dim3(256), dim3(512), 0, stream>>>(wsA, wsB, indices, out);
    } else {
        spmm_dt_fallback<<<dim3(NB / 128, OUT_F / 128), dim3(256), 0, stream>>>(
            weight, indices, metadata, input, out);
    }
}

// Round 4
// 362.488 us; speedup vs baseline: 1.0381x; 1.0381x over previous
//
#include <hip/hip_runtime.h>

#define OUT_F 4096   // compressed rows
#define IN_F  2048   // compressed cols
#define KLOG  4096   // logical k = 2*IN_F
#define NB    4096   // batch
typedef unsigned long long ull;
typedef ull ullx2 __attribute__((ext_vector_type(2)));

typedef __bf16 bf16x8 __attribute__((ext_vector_type(8)));
typedef short  s16x8  __attribute__((ext_vector_type(8)));
typedef float  f32x4  __attribute__((ext_vector_type(4)));
typedef float  f32x16 __attribute__((ext_vector_type(16)));

__device__ __forceinline__ unsigned short f2bf(float f) {
    unsigned int u = __float_as_uint(f);
    u += 0x7fffu + ((u >> 16) & 1u);
    return (unsigned short)(u >> 16);
}

__device__ __forceinline__ void gload_lds16(const void* g, void* l) {
    __builtin_amdgcn_global_load_lds(
        (const __attribute__((address_space(1))) unsigned int*)g,
        (__attribute__((address_space(3))) unsigned int*)l, 16, 0, 0);
}

__device__ __forceinline__ bf16x8 ldsf(const char* p) {
    return __builtin_bit_cast(bf16x8, *(const s16x8*)p);
}

#define MFMA32(a, b, c) __builtin_amdgcn_mfma_f32_32x32x16_bf16((a), (b), (c), 0, 0, 0)

// ---------- Pre-pass: [0,4096) decompress weight -> bf16 wsA; [4096,8192) input -> bf16 wsB.
__global__ __launch_bounds__(256) void prep_kernel(
    const float* __restrict__ weight, const int* __restrict__ metadata,
    const float* __restrict__ input,
    unsigned short* __restrict__ wsA, unsigned short* __restrict__ wsB)
{
    const int b = blockIdx.x;
    if (b < 4096) {
        const int g = b * 256 + threadIdx.x;
        const int r = g >> 8;
        const int c = (g & 255) * 8;
        const size_t off = (size_t)r * IN_F + c;
        const float4 w0 = *(const float4*)(weight + off);
        const float4 w1 = *(const float4*)(weight + off + 4);
        const int4   m0 = *(const int4*)(metadata + off);
        const int4   m1 = *(const int4*)(metadata + off + 4);
        ullx2 v01, v23;
        v01.x = ((ull)f2bf(w0.x) << (m0.x * 16)) | ((ull)f2bf(w0.y) << (m0.y * 16));
        v01.y = ((ull)f2bf(w0.z) << (m0.z * 16)) | ((ull)f2bf(w0.w) << (m0.w * 16));
        v23.x = ((ull)f2bf(w1.x) << (m1.x * 16)) | ((ull)f2bf(w1.y) << (m1.y * 16));
        v23.y = ((ull)f2bf(w1.z) << (m1.z * 16)) | ((ull)f2bf(w1.w) << (m1.w * 16));
        ull* dst = (ull*)(wsA + (size_t)r * KLOG + 2 * c);
        *(ullx2*)(dst)     = v01;
        *(ullx2*)(dst + 2) = v23;
    } else {
        const int g = (b - 4096) * 256 + threadIdx.x;
        const size_t off = (size_t)g * 16;
        const float4 f0 = *(const float4*)(input + off);
        const float4 f1 = *(const float4*)(input + off + 4);
        const float4 f2 = *(const float4*)(input + off + 8);
        const float4 f3 = *(const float4*)(input + off + 12);
        ullx2 v01, v23;
        v01.x =  (ull)f2bf(f0.x) | ((ull)f2bf(f0.y) << 16) | ((ull)f2bf(f0.z) << 32) | ((ull)f2bf(f0.w) << 48);
        v01.y =  (ull)f2bf(f1.x) | ((ull)f2bf(f1.y) << 16) | ((ull)f2bf(f1.z) << 32) | ((ull)f2bf(f1.w) << 48);
        v23.x =  (ull)f2bf(f2.x) | ((ull)f2bf(f2.y) << 16) | ((ull)f2bf(f2.z) << 32) | ((ull)f2bf(f2.w) << 48);
        v23.y =  (ull)f2bf(f3.x) | ((ull)f2bf(f3.y) << 16) | ((ull)f2bf(f3.z) << 32) | ((ull)f2bf(f3.w) << 48);
        ull* dst = (ull*)(wsB + off);
        *(ullx2*)(dst)     = v01;
        *(ullx2*)(dst + 2) = v23;
    }
}

// ---------- Main GEMM: 256x256 tile, 8 waves (2M x 4N), BK=32, 32x32x16 bf16 MFMA.
// Ring-4 LDS (128 KB), depth-3 prefetch, counted vmcnt(8) once per K-tile.
// m201-style cadence: iteration = 2 K-tiles, 4 dual-barrier phases; each phase's
// MFMA cluster touches one acc row-pair only (acc recurrence distance = 1 phase-pair),
// so the matrix pipe drains its backlog THROUGH the next phase's read region.
// B-fragments held in registers across the phase pair (LDS traffic unchanged).
// Swizzle: phys 16B-chunk = logical ^ ((row>>1)&3)  (verified, carried over).
__global__ __launch_bounds__(512, 2) void gemm_kernel256(
    const unsigned short* __restrict__ wsA, const unsigned short* __restrict__ wsB,
    const int* __restrict__ indices, float* __restrict__ out)
{
    // 4 ring buffers x (A 256x32 bf16 = 16 KB, B 256x32 bf16 = 16 KB) = 128 KB
    __shared__ __align__(16) char lds[4 * 32768];

    const int tid  = threadIdx.x;
    const int lane = tid & 63;
    const int wave = tid >> 6;
    const int wm   = wave >> 2;   // 0..1 : 128-row half of the M-tile
    const int wn   = wave & 3;    // 0..3 : 64-col strip of the N-tile
    const int l31  = lane & 31;
    const int h    = lane >> 5;   // k-half of fragment

    // T1: XCD-aware swizzle. 256 blocks, 8 XCDs -> XCD x gets 32 consecutive tile ids.
    const int swz = ((blockIdx.x & 7) << 5) | (blockIdx.x >> 3);
    const int r0 = (swz >> 4) << 8;   // M origin
    const int b0 = (swz & 15) << 8;   // N origin

    // ---- staging: one call covers 128 rows x 32 cols (8 KB), 16B/thread ----
    const int srow   = tid >> 2;                      // 0..127
    const int schunk = (tid & 3) ^ ((tid >> 3) & 3);  // pre-swizzled source 16B-chunk
    const unsigned short* gA = wsA + (size_t)(r0 + srow) * KLOG + schunk * 8;
    const unsigned short* gB = wsB + (size_t)(b0 + srow) * KLOG + schunk * 8;
    char* const ldsW = lds + wave * 1024;             // wave-uniform staging base

    // ---- fragment-read constants ----
    const int q = (l31 >> 1) & 3;                      // == (row>>1)&3 for all frag rows
    const unsigned x0 = (unsigned)(((0 + h) ^ q) * 16);  // k-step 0: logical chunks {0,1}
    const unsigned x1 = (unsigned)(((2 + h) ^ q) * 16);  // k-step 1: logical chunks {2,3}
    const unsigned aRow = (unsigned)((wm * 128 + l31) * 64);
    const unsigned bRow = (unsigned)((wn * 64  + l31) * 64);

    f32x16 acc[4][2];
#pragma unroll
    for (int i = 0; i < 4; ++i)
#pragma unroll
        for (int j = 0; j < 2; ++j)
#pragma unroll
            for (int e = 0; e < 16; ++e) acc[i][j][e] = 0.f;

#define STAGE_A(t_) do { \
        char* _d = ldsW + (((t_) & 3) * 32768); \
        const unsigned short* _s = gA + (t_) * 32; \
        gload_lds16(_s, _d); \
        gload_lds16(_s + (size_t)128 * KLOG, _d + 8192); } while (0)
#define STAGE_B(t_) do { \
        char* _d = ldsW + (((t_) & 3) * 32768) + 16384; \
        const unsigned short* _s = gB + (t_) * 32; \
        gload_lds16(_s, _d); \
        gload_lds16(_s + (size_t)128 * KLOG, _d + 8192); } while (0)

#define BAR()      __builtin_amdgcn_s_barrier()
#define SCHED0()   __builtin_amdgcn_sched_barrier(0)
#define LGKM0()    asm volatile("s_waitcnt lgkmcnt(0)" ::: "memory")

    // prologue: stage tiles 0,1,2 (12 loads/thread); wait oldest 4 (= tile 0)
    STAGE_A(0); STAGE_B(0);
    STAGE_A(1); STAGE_B(1);
    STAGE_A(2); STAGE_B(2);
    asm volatile("s_waitcnt vmcnt(8)" ::: "memory");
    BAR();
    SCHED0();

    for (int i = 0; i < 64; ++i) {
        const int ta = 2 * i, tb = 2 * i + 1;
        const char* pAa = lds + (unsigned)(ta & 3) * 32768u + aRow;
        const char* pBa = lds + (unsigned)(ta & 3) * 32768u + 16384u + bRow;
        const char* pAb = lds + (unsigned)(tb & 3) * 32768u + aRow;
        const char* pBb = lds + (unsigned)(tb & 3) * 32768u + 16384u + bRow;

        // ---------- phase 0: tile ta, acc rows 0,1 (B loaded for the pair) ----------
        bf16x8 b00 = ldsf(pBa + x0);
        bf16x8 b10 = ldsf(pBa + 2048 + x0);
        bf16x8 b01 = ldsf(pBa + x1);
        bf16x8 b11 = ldsf(pBa + 2048 + x1);
        bf16x8 a00 = ldsf(pAa + x0);
        bf16x8 a01 = ldsf(pAa + x1);
        bf16x8 a10 = ldsf(pAa + 2048 + x0);
        bf16x8 a11 = ldsf(pAa + 2048 + x1);
        if (i <= 62) STAGE_A(ta + 3);
        BAR();
        LGKM0();
        SCHED0();
        __builtin_amdgcn_s_setprio(1);
        acc[0][0] = MFMA32(a00, b00, acc[0][0]);
        acc[0][1] = MFMA32(a00, b10, acc[0][1]);
        acc[1][0] = MFMA32(a10, b00, acc[1][0]);
        acc[1][1] = MFMA32(a10, b10, acc[1][1]);
        acc[0][0] = MFMA32(a01, b01, acc[0][0]);
        acc[0][1] = MFMA32(a01, b11, acc[0][1]);
        acc[1][0] = MFMA32(a11, b01, acc[1][0]);
        acc[1][1] = MFMA32(a11, b11, acc[1][1]);
        __builtin_amdgcn_s_setprio(0);
        BAR();
        SCHED0();

        // ---------- phase 1: tile ta, acc rows 2,3 (reuses b00..b11) ----------
        bf16x8 a20 = ldsf(pAa + 4096 + x0);
        bf16x8 a21 = ldsf(pAa + 4096 + x1);
        bf16x8 a30 = ldsf(pAa + 6144 + x0);
        bf16x8 a31 = ldsf(pAa + 6144 + x1);
        if (i <= 62) STAGE_B(ta + 3);
        BAR();
        LGKM0();
        SCHED0();
        __builtin_amdgcn_s_setprio(1);
        acc[2][0] = MFMA32(a20, b00, acc[2][0]);
        acc[2][1] = MFMA32(a20, b10, acc[2][1]);
        acc[3][0] = MFMA32(a30, b00, acc[3][0]);
        acc[3][1] = MFMA32(a30, b10, acc[3][1]);
        acc[2][0] = MFMA32(a21, b01, acc[2][0]);
        acc[2][1] = MFMA32(a21, b11, acc[2][1]);
        acc[3][0] = MFMA32(a31, b01, acc[3][0]);
        acc[3][1] = MFMA32(a31, b11, acc[3][1]);
        __builtin_amdgcn_s_setprio(0);
        // counted vmcnt, once per K-tile: tile tb's loads (issued 8 loads ago) must be done.
        if (i < 63) { asm volatile("s_waitcnt vmcnt(8)" ::: "memory"); }
        else        { asm volatile("s_waitcnt vmcnt(0)" ::: "memory"); }
        BAR();
        SCHED0();

        // ---------- phase 2: tile tb, acc rows 0,1 ----------
        b00 = ldsf(pBb + x0);
        b10 = ldsf(pBb + 2048 + x0);
        b01 = ldsf(pBb + x1);
        b11 = ldsf(pBb + 2048 + x1);
        a00 = ldsf(pAb + x0);
        a01 = ldsf(pAb + x1);
        a10 = ldsf(pAb + 2048 + x0);
        a11 = ldsf(pAb + 2048 + x1);
        if (i <= 61) STAGE_A(tb + 3);
        BAR();
        LGKM0();
        SCHED0();
        __builtin_amdgcn_s_setprio(1);
        acc[0][0] = MFMA32(a00, b00, acc[0][0]);
        acc[0][1] = MFMA32(a00, b10, acc[0][1]);
        acc[1][0] = MFMA32(a10, b00, acc[1][0]);
        acc[1][1] = MFMA32(a10, b10, acc[1][1]);
        acc[0][0] = MFMA32(a01, b01, acc[0][0]);
        acc[0][1] = MFMA32(a01, b11, acc[0][1]);
        acc[1][0] = MFMA32(a11, b01, acc[1][0]);
        acc[1][1] = MFMA32(a11, b11, acc[1][1]);
        __builtin_amdgcn_s_setprio(0);
        BAR();
        SCHED0();

        // ---------- phase 3: tile tb, acc rows 2,3 ----------
        a20 = ldsf(pAb + 4096 + x0);
        a21 = ldsf(pAb + 4096 + x1);
        a30 = ldsf(pAb + 6144 + x0);
        a31 = ldsf(pAb + 6144 + x1);
        if (i <= 61) STAGE_B(tb + 3);
        BAR();
        LGKM0();
        SCHED0();
        __builtin_amdgcn_s_setprio(1);
        acc[2][0] = MFMA32(a20, b00, acc[2][0]);
        acc[2][1] = MFMA32(a20, b10, acc[2][1]);
        acc[3][0] = MFMA32(a30, b00, acc[3][0]);
        acc[3][1] = MFMA32(a30, b10, acc[3][1]);
        acc[2][0] = MFMA32(a21, b01, acc[2][0]);
        acc[2][1] = MFMA32(a21, b11, acc[2][1]);
        acc[3][0] = MFMA32(a31, b01, acc[3][0]);
        acc[3][1] = MFMA32(a31, b11, acc[3][1]);
        __builtin_amdgcn_s_setprio(0);
        // next iteration's first reads hit tile ta+2 (staged last iteration):
        // newest 8 outstanding loads are tiles ta+3 / tb+3 -> vmcnt(8).
        if (i <= 61)      { asm volatile("s_waitcnt vmcnt(8)" ::: "memory"); }
        else if (i == 62) { asm volatile("s_waitcnt vmcnt(4)" ::: "memory"); }
        BAR();
        SCHED0();
    }
#undef STAGE_A
#undef STAGE_B
#undef BAR
#undef SCHED0
#undef LGKM0

    // epilogue: C/D (32x32): col = l31, row = (reg&3) + 8*(reg>>2) + 4*h  [m74/m101]
#pragma unroll
    for (int fm = 0; fm < 4; ++fm) {
#pragma unroll
        for (int reg = 0; reg < 16; ++reg) {
            const int rloc = wm * 128 + fm * 32 + (reg & 3) + 8 * (reg >> 2) + 4 * h;
            const int L = indices[r0 + rloc];
            const size_t base  = (size_t)L * NB;
            const size_t baseZ = (size_t)(L ^ 1) * NB;
#pragma unroll
            for (int fn = 0; fn < 2; ++fn) {
                const int col = b0 + wn * 64 + fn * 32 + l31;
                out[base  + col] = acc[fm][fn][reg];
                out[baseZ + col] = 0.0f;
            }
        }
    }
}

// ---------- Fallback (round-1 fused kernel) if ws is too small ----------
__global__ __launch_bounds__(256) void spmm_dt_fallback(
    const float* __restrict__ weight, const int* __restrict__ indices,
    const int* __restrict__ metadata, const float* __restrict__ input,
    float* __restrict__ out)
{
    __shared__ __align__(16) unsigned short As[128][32];
    __shared__ __align__(16) unsigned short Bs[128][32];
    const int tid = threadIdx.x, lane = tid & 63, wave = tid >> 6;
    const int wm = wave >> 1, wn = wave & 1, l15 = lane & 15, quad = lane >> 4;
    const int r0 = blockIdx.y * 128, b0 = blockIdx.x * 128;
    f32x4 acc[4][4];
#pragma unroll
    for (int i = 0; i < 4; ++i)
#pragma unroll
        for (int j = 0; j < 4; ++j) acc[i][j] = (f32x4){0.f, 0.f, 0.f, 0.f};
    const int srow = tid >> 3, sgrp = tid & 7;
    for (int kk = 0; kk < KLOG / 32; ++kk) {
        const int c0 = kk * 16, k0 = kk * 32;
#pragma unroll
        for (int s = 0; s < 4; ++s) {
            const int row = srow + s * 32;
            const size_t off = (size_t)(r0 + row) * IN_F + c0 + 2 * sgrp;
            const float2 w = *(const float2*)(weight + off);
            const int2  md = *(const int2*)(metadata + off);
            *(ull*)(&As[row][4 * sgrp]) =
                ((ull)f2bf(w.x) << (md.x * 16)) | ((ull)f2bf(w.y) << (md.y * 16));
        }
#pragma unroll
        for (int s = 0; s < 4; ++s) {
            const int row = srow + s * 32;
            const float4 f = *(const float4*)(&input[(size_t)(b0 + row) * KLOG + k0 + sgrp * 4]);
            *(ull*)(&Bs[row][sgrp * 4]) =
                 (ull)f2bf(f.x) | ((ull)f2bf(f.y) << 16) |
                ((ull)f2bf(f.z) << 32) | ((ull)f2bf(f.w) << 48);
        }
        __syncthreads();
        bf16x8 a[4], b[4];
#pragma unroll
        for (int i = 0; i < 4; ++i)
            a[i] = __builtin_bit_cast(bf16x8, *(const s16x8*)(&As[wm * 64 + i * 16 + l15][quad * 8]));
#pragma unroll
        for (int j = 0; j < 4; ++j)
            b[j] = __builtin_bit_cast(bf16x8, *(const s16x8*)(&Bs[wn * 64 + j * 16 + l15][quad * 8]));
#pragma unroll
        for (int i = 0; i < 4; ++i)
#pragma unroll
            for (int j = 0; j < 4; ++j)
                acc[i][j] = __builtin_amdgcn_mfma_f32_16x16x32_bf16(a[i], b[j], acc[i][j], 0, 0, 0);
        __syncthreads();
    }
#pragma unroll
    for (int i = 0; i < 4; ++i)
#pragma unroll
        for (int t = 0; t < 4; ++t) {
            const int r = r0 + wm * 64 + i * 16 + quad * 4 + t;
            const int L = indices[r];
            const size_t base = (size_t)L * NB, baseZ = (size_t)(L ^ 1) * NB;
#pragma unroll
            for (int j = 0; j < 4; ++j) {
                const int col = b0 + wn * 64 + j * 16 + l15;
                out[base + col] = acc[i][j][t];
                out[baseZ + col] = 0.0f;
            }
        }
}

extern "C" void kernel_launch(void* const* d_in, const int* in_sizes, int n_in,
                              void* d_out, int out_size, void* d_ws, size_t ws_size,
                              hipStream_t stream) {
    const float* weight   = (const float*)d_in[0];
    const int*   indices  = (const int*)d_in[1];
    const int*   metadata = (const int*)d_in[2];
    const float* input    = (const float*)d_in[3];
    float*       out      = (float*)d_out;

    const size_t needA = (size_t)OUT_F * KLOG * 2;  // 32 MB
    const size_t needB = (size_t)NB * KLOG * 2;     // 32 MB
    if (ws_size >= needA + needB) {
        unsigned short* wsA = (unsigned short*)d_ws;
        unsigned short* wsB = wsA + (size_t)OUT_F * KLOG;
        prep_kernel<<<dim3(8192), dim3(256), 0, stream>>>(weight, metadata, input, wsA, wsB);
        gemm_kernel256<<<dim3(256), dim3(512), 0, stream>>>(wsA, wsB, indices, out);
    } else {
        spmm_dt_fallback<<<dim3(NB / 128, OUT_F / 128), dim3(256), 0, stream>>>(
            weight, indices, metadata, input, out);
    }
}

// Round 5
// 357.236 us; speedup vs baseline: 1.0534x; 1.0147x over previous
//
#include <hip/hip_runtime.h>

#define OUT_F 4096   // compressed rows
#define IN_F  2048   // compressed cols
#define KLOG  4096   // logical k = 2*IN_F
#define NB    4096   // batch
typedef unsigned long long ull;
typedef ull ullx2 __attribute__((ext_vector_type(2)));

typedef __bf16 bf16x8 __attribute__((ext_vector_type(8)));
typedef short  s16x8  __attribute__((ext_vector_type(8)));
typedef float  f32x4  __attribute__((ext_vector_type(4)));
typedef float  f32x16 __attribute__((ext_vector_type(16)));

__device__ __forceinline__ unsigned short f2bf(float f) {
    unsigned int u = __float_as_uint(f);
    u += 0x7fffu + ((u >> 16) & 1u);
    return (unsigned short)(u >> 16);
}

__device__ __forceinline__ void gload_lds16(const void* g, void* l) {
    __builtin_amdgcn_global_load_lds(
        (const __attribute__((address_space(1))) unsigned int*)g,
        (__attribute__((address_space(3))) unsigned int*)l, 16, 0, 0);
}

__device__ __forceinline__ bf16x8 ldsf(const char* p) {
    return __builtin_bit_cast(bf16x8, *(const s16x8*)p);
}

#define MFMA32(a, b, c) __builtin_amdgcn_mfma_f32_32x32x16_bf16((a), (b), (c), 0, 0, 0)

// ---------- Pre-pass: [0,4096) decompress weight -> bf16 wsA; [4096,8192) input -> bf16 wsB.
__global__ __launch_bounds__(256) void prep_kernel(
    const float* __restrict__ weight, const int* __restrict__ metadata,
    const float* __restrict__ input,
    unsigned short* __restrict__ wsA, unsigned short* __restrict__ wsB)
{
    const int b = blockIdx.x;
    if (b < 4096) {
        const int g = b * 256 + threadIdx.x;
        const int r = g >> 8;
        const int c = (g & 255) * 8;
        const size_t off = (size_t)r * IN_F + c;
        const float4 w0 = *(const float4*)(weight + off);
        const float4 w1 = *(const float4*)(weight + off + 4);
        const int4   m0 = *(const int4*)(metadata + off);
        const int4   m1 = *(const int4*)(metadata + off + 4);
        ullx2 v01, v23;
        v01.x = ((ull)f2bf(w0.x) << (m0.x * 16)) | ((ull)f2bf(w0.y) << (m0.y * 16));
        v01.y = ((ull)f2bf(w0.z) << (m0.z * 16)) | ((ull)f2bf(w0.w) << (m0.w * 16));
        v23.x = ((ull)f2bf(w1.x) << (m1.x * 16)) | ((ull)f2bf(w1.y) << (m1.y * 16));
        v23.y = ((ull)f2bf(w1.z) << (m1.z * 16)) | ((ull)f2bf(w1.w) << (m1.w * 16));
        ull* dst = (ull*)(wsA + (size_t)r * KLOG + 2 * c);
        *(ullx2*)(dst)     = v01;
        *(ullx2*)(dst + 2) = v23;
    } else {
        const int g = (b - 4096) * 256 + threadIdx.x;
        const size_t off = (size_t)g * 16;
        const float4 f0 = *(const float4*)(input + off);
        const float4 f1 = *(const float4*)(input + off + 4);
        const float4 f2 = *(const float4*)(input + off + 8);
        const float4 f3 = *(const float4*)(input + off + 12);
        ullx2 v01, v23;
        v01.x =  (ull)f2bf(f0.x) | ((ull)f2bf(f0.y) << 16) | ((ull)f2bf(f0.z) << 32) | ((ull)f2bf(f0.w) << 48);
        v01.y =  (ull)f2bf(f1.x) | ((ull)f2bf(f1.y) << 16) | ((ull)f2bf(f1.z) << 32) | ((ull)f2bf(f1.w) << 48);
        v23.x =  (ull)f2bf(f2.x) | ((ull)f2bf(f2.y) << 16) | ((ull)f2bf(f2.z) << 32) | ((ull)f2bf(f2.w) << 48);
        v23.y =  (ull)f2bf(f3.x) | ((ull)f2bf(f3.y) << 16) | ((ull)f2bf(f3.z) << 32) | ((ull)f2bf(f3.w) << 48);
        ull* dst = (ull*)(wsB + off);
        *(ullx2*)(dst)     = v01;
        *(ullx2*)(dst + 2) = v23;
    }
}

// ---------- Main GEMM: 256x256 tile, 8 waves (2M x 4N), BK=32, 32x32x16 bf16 MFMA.
// Ring-4 LDS (128 KB), depth-3 prefetch, counted vmcnt(4) once per K-tile.
// CROSS-TILE fragment double-buffering: tile t's MFMAs consume fragments read in
// tile t-1 (B + A-k0 prefetched; A-k1 read at own-tile start, drained by lgkmcnt(8)).
// Counted lgkmcnt(12/8) — never 0 in the main loop — so DS reads complete UNDER the
// MFMA shadow instead of serializing read-burst + MFMA-burst (the R1/R4 limit).
// Steady-state DS FIFO: [prev-prefetch 8][k1 4][nxt 8]; lgkm(12) drains prev, lgkm(8) drains k1.
// vmcnt invariant: at start of tile t, buf[t+1] complete (end-of-(t-1) vmcnt(4)).
// Swizzle: phys 16B-chunk = logical ^ ((row>>1)&3)  (verified, carried over).
__global__ __launch_bounds__(512, 2) void gemm_kernel256(
    const unsigned short* __restrict__ wsA, const unsigned short* __restrict__ wsB,
    const int* __restrict__ indices, float* __restrict__ out)
{
    __shared__ __align__(16) char lds[4 * 32768];

    const int tid  = threadIdx.x;
    const int lane = tid & 63;
    const int wave = tid >> 6;
    const int wm   = wave >> 2;   // 0..1 : 128-row half of the M-tile
    const int wn   = wave & 3;    // 0..3 : 64-col strip of the N-tile
    const int l31  = lane & 31;
    const int h    = lane >> 5;   // k-half of fragment

    const int swz = ((blockIdx.x & 7) << 5) | (blockIdx.x >> 3);
    const int r0 = (swz >> 4) << 8;   // M origin
    const int b0 = (swz & 15) << 8;   // N origin

    const int srow   = tid >> 2;                      // 0..127
    const int schunk = (tid & 3) ^ ((tid >> 3) & 3);  // pre-swizzled source 16B-chunk
    const unsigned short* gA = wsA + (size_t)(r0 + srow) * KLOG + schunk * 8;
    const unsigned short* gB = wsB + (size_t)(b0 + srow) * KLOG + schunk * 8;
    char* const ldsW = lds + wave * 1024;             // wave-uniform staging base

    const int q = (l31 >> 1) & 3;
    const unsigned x0 = (unsigned)(((0 + h) ^ q) * 16);  // k-step 0: logical chunks {0,1}
    const unsigned x1 = (unsigned)(((2 + h) ^ q) * 16);  // k-step 1: logical chunks {2,3}
    const unsigned aRow = (unsigned)((wm * 128 + l31) * 64);
    const unsigned bRow = (unsigned)((wn * 64  + l31) * 64);

    f32x16 acc[4][2];
#pragma unroll
    for (int i = 0; i < 4; ++i)
#pragma unroll
        for (int j = 0; j < 2; ++j)
#pragma unroll
            for (int e = 0; e < 16; ++e) acc[i][j][e] = 0.f;

    // prefetch sets: [0..3] = B {b00,b10,b01,b11}; [4..7] = A-k0 {a0..a3}
    bf16x8 pf0[8], pf1[8];
    bf16x8 k1_0, k1_1, k1_2, k1_3;    // own-tile A-k1 fragments (transient)

#define STAGE_A(t_) do { \
        char* _d = ldsW + (((t_) & 3) * 32768); \
        const unsigned short* _s = gA + (t_) * 32; \
        gload_lds16(_s, _d); \
        gload_lds16(_s + (size_t)128 * KLOG, _d + 8192); } while (0)
#define STAGE_B(t_) do { \
        char* _d = ldsW + (((t_) & 3) * 32768) + 16384; \
        const unsigned short* _s = gB + (t_) * 32; \
        gload_lds16(_s, _d); \
        gload_lds16(_s + (size_t)128 * KLOG, _d + 8192); } while (0)

#define BAR()     __builtin_amdgcn_s_barrier()
#define SCHED0()  __builtin_amdgcn_sched_barrier(0)
#define LGKM(n_)  asm volatile("s_waitcnt lgkmcnt(" #n_ ")" ::: "memory")
#define VMC(n_)   asm volatile("s_waitcnt vmcnt(" #n_ ")" ::: "memory")

    // k1 reads of THIS tile (issued first → drained by mid-tile lgkm(8)),
    // then next-tile prefetch (B + A-k0) into NXT.
#define READS(t_, NXT) do { \
        const char* pA1 = lds + (unsigned)((t_) & 3) * 32768u + aRow; \
        k1_0 = ldsf(pA1 + x1); \
        k1_1 = ldsf(pA1 + 2048 + x1); \
        k1_2 = ldsf(pA1 + 4096 + x1); \
        k1_3 = ldsf(pA1 + 6144 + x1); \
        const unsigned bO = (unsigned)(((t_) + 1) & 3) * 32768u; \
        const char* pB = lds + bO + 16384u + bRow; \
        const char* pA = lds + bO + aRow; \
        NXT[0] = ldsf(pB + x0); \
        NXT[1] = ldsf(pB + 2048 + x0); \
        NXT[2] = ldsf(pB + x1); \
        NXT[3] = ldsf(pB + 2048 + x1); \
        NXT[4] = ldsf(pA + x0); \
        NXT[5] = ldsf(pA + 2048 + x0); \
        NXT[6] = ldsf(pA + 4096 + x0); \
        NXT[7] = ldsf(pA + 6144 + x0); } while (0)

#define MFMAS_K0(CUR) \
        acc[0][0] = MFMA32(CUR[4], CUR[0], acc[0][0]); \
        acc[0][1] = MFMA32(CUR[4], CUR[1], acc[0][1]); \
        acc[1][0] = MFMA32(CUR[5], CUR[0], acc[1][0]); \
        acc[1][1] = MFMA32(CUR[5], CUR[1], acc[1][1]); \
        acc[2][0] = MFMA32(CUR[6], CUR[0], acc[2][0]); \
        acc[2][1] = MFMA32(CUR[6], CUR[1], acc[2][1]); \
        acc[3][0] = MFMA32(CUR[7], CUR[0], acc[3][0]); \
        acc[3][1] = MFMA32(CUR[7], CUR[1], acc[3][1]);

#define MFMAS_K1(CUR) \
        acc[0][0] = MFMA32(k1_0, CUR[2], acc[0][0]); \
        acc[0][1] = MFMA32(k1_0, CUR[3], acc[0][1]); \
        acc[1][0] = MFMA32(k1_1, CUR[2], acc[1][0]); \
        acc[1][1] = MFMA32(k1_1, CUR[3], acc[1][1]); \
        acc[2][0] = MFMA32(k1_2, CUR[2], acc[2][0]); \
        acc[2][1] = MFMA32(k1_2, CUR[3], acc[2][1]); \
        acc[3][0] = MFMA32(k1_3, CUR[2], acc[3][0]); \
        acc[3][1] = MFMA32(k1_3, CUR[3], acc[3][1]);

    // ---- prologue: stage tiles 0,1,2; drain tiles 0,1 (vmcnt(4)); prefetch tile-0 frags ----
    STAGE_A(0); STAGE_B(0);
    STAGE_A(1); STAGE_B(1);
    STAGE_A(2); STAGE_B(2);
    VMC(4);                       // 12 outstanding -> 8 oldest (tiles 0,1) done
    BAR();
    SCHED0();
    {
        const char* pB = lds + 16384u + bRow;
        const char* pA = lds + aRow;
        pf0[0] = ldsf(pB + x0);
        pf0[1] = ldsf(pB + 2048 + x0);
        pf0[2] = ldsf(pB + x1);
        pf0[3] = ldsf(pB + 2048 + x1);
        pf0[4] = ldsf(pA + x0);
        pf0[5] = ldsf(pA + 2048 + x0);
        pf0[6] = ldsf(pA + 4096 + x0);
        pf0[7] = ldsf(pA + 6144 + x0);
    }

    // ---- main loop: tiles 0..125 (pairs), peel 126/127 ----
    for (int i = 0; i < 63; ++i) {
        const int ta = 2 * i, tb = 2 * i + 1;

        // ======== tile ta (even): CUR=pf0, NXT=pf1 ========
        READS(ta, pf1);
        STAGE_A(ta + 3); STAGE_B(ta + 3);          // ta+3 <= 127
        SCHED0();
        LGKM(12); SCHED0();                        // prev prefetch (pf0) ready
        __builtin_amdgcn_s_setprio(1);
        MFMAS_K0(pf0)
        LGKM(8); SCHED0();                         // own k1 reads ready
        MFMAS_K1(pf0)
        __builtin_amdgcn_s_setprio(0);
        VMC(4);                                    // buf[ta+2] complete, ta+3 in flight
        BAR();
        SCHED0();

        // ======== tile tb (odd): CUR=pf1, NXT=pf0 ========
        READS(tb, pf0);
        if (tb <= 124) { STAGE_A(tb + 3); STAGE_B(tb + 3); }
        SCHED0();
        LGKM(12); SCHED0();
        __builtin_amdgcn_s_setprio(1);
        MFMAS_K0(pf1)
        LGKM(8); SCHED0();
        MFMAS_K1(pf1)
        __builtin_amdgcn_s_setprio(0);
        if (tb <= 124) { VMC(4); }                 // buf[tb+2] complete
        else           { VMC(0); }                 // tb==125: drain buf[127]
        BAR();
        SCHED0();
    }

    // ======== tile 126 (even): CUR=pf0, NXT=pf1; no staging, nothing outstanding ========
    READS(126, pf1);                               // k1 from buf[2], frags of 127 from buf[3]
    SCHED0();
    LGKM(12); SCHED0();
    __builtin_amdgcn_s_setprio(1);
    MFMAS_K0(pf0)
    LGKM(8); SCHED0();
    MFMAS_K1(pf0)
    __builtin_amdgcn_s_setprio(0);
    BAR();
    SCHED0();

    // ======== tile 127 (odd): CUR=pf1; k1 reads only ========
    {
        const char* pA1 = lds + (unsigned)(127 & 3) * 32768u + aRow;
        k1_0 = ldsf(pA1 + x1);
        k1_1 = ldsf(pA1 + 2048 + x1);
        k1_2 = ldsf(pA1 + 4096 + x1);
        k1_3 = ldsf(pA1 + 6144 + x1);
    }
    SCHED0();
    LGKM(4); SCHED0();                             // pf1 prefetch (8 reads) done
    __builtin_amdgcn_s_setprio(1);
    MFMAS_K0(pf1)
    LGKM(0); SCHED0();
    MFMAS_K1(pf1)
    __builtin_amdgcn_s_setprio(0);

#undef STAGE_A
#undef STAGE_B
#undef BAR
#undef SCHED0
#undef LGKM
#undef VMC
#undef READS
#undef MFMAS_K0
#undef MFMAS_K1

    // epilogue: C/D (32x32): col = l31, row = (reg&3) + 8*(reg>>2) + 4*h  [m74/m101]
#pragma unroll
    for (int fm = 0; fm < 4; ++fm) {
#pragma unroll
        for (int reg = 0; reg < 16; ++reg) {
            const int rloc = wm * 128 + fm * 32 + (reg & 3) + 8 * (reg >> 2) + 4 * h;
            const int L = indices[r0 + rloc];
            const size_t base  = (size_t)L * NB;
            const size_t baseZ = (size_t)(L ^ 1) * NB;
#pragma unroll
            for (int fn = 0; fn < 2; ++fn) {
                const int col = b0 + wn * 64 + fn * 32 + l31;
                out[base  + col] = acc[fm][fn][reg];
                out[baseZ + col] = 0.0f;
            }
        }
    }
}

// ---------- Fallback (round-1 fused kernel) if ws is too small ----------
__global__ __launch_bounds__(256) void spmm_dt_fallback(
    const float* __restrict__ weight, const int* __restrict__ indices,
    const int* __restrict__ metadata, const float* __restrict__ input,
    float* __restrict__ out)
{
    __shared__ __align__(16) unsigned short As[128][32];
    __shared__ __align__(16) unsigned short Bs[128][32];
    const int tid = threadIdx.x, lane = tid & 63, wave = tid >> 6;
    const int wm = wave >> 1, wn = wave & 1, l15 = lane & 15, quad = lane >> 4;
    const int r0 = blockIdx.y * 128, b0 = blockIdx.x * 128;
    f32x4 acc[4][4];
#pragma unroll
    for (int i = 0; i < 4; ++i)
#pragma unroll
        for (int j = 0; j < 4; ++j) acc[i][j] = (f32x4){0.f, 0.f, 0.f, 0.f};
    const int srow = tid >> 3, sgrp = tid & 7;
    for (int kk = 0; kk < KLOG / 32; ++kk) {
        const int c0 = kk * 16, k0 = kk * 32;
#pragma unroll
        for (int s = 0; s < 4; ++s) {
            const int row = srow + s * 32;
            const size_t off = (size_t)(r0 + row) * IN_F + c0 + 2 * sgrp;
            const float2 w = *(const float2*)(weight + off);
            const int2  md = *(const int2*)(metadata + off);
            *(ull*)(&As[row][4 * sgrp]) =
                ((ull)f2bf(w.x) << (md.x * 16)) | ((ull)f2bf(w.y) << (md.y * 16));
        }
#pragma unroll
        for (int s = 0; s < 4; ++s) {
            const int row = srow + s * 32;
            const float4 f = *(const float4*)(&input[(size_t)(b0 + row) * KLOG + k0 + sgrp * 4]);
            *(ull*)(&Bs[row][sgrp * 4]) =
                 (ull)f2bf(f.x) | ((ull)f2bf(f.y) << 16) |
                ((ull)f2bf(f.z) << 32) | ((ull)f2bf(f.w) << 48);
        }
        __syncthreads();
        bf16x8 a[4], b[4];
#pragma unroll
        for (int i = 0; i < 4; ++i)
            a[i] = __builtin_bit_cast(bf16x8, *(const s16x8*)(&As[wm * 64 + i * 16 + l15][quad * 8]));
#pragma unroll
        for (int j = 0; j < 4; ++j)
            b[j] = __builtin_bit_cast(bf16x8, *(const s16x8*)(&Bs[wn * 64 + j * 16 + l15][quad * 8]));
#pragma unroll
        for (int i = 0; i < 4; ++i)
#pragma unroll
            for (int j = 0; j < 4; ++j)
                acc[i][j] = __builtin_amdgcn_mfma_f32_16x16x32_bf16(a[i], b[j], acc[i][j], 0, 0, 0);
        __syncthreads();
    }
#pragma unroll
    for (int i = 0; i < 4; ++i)
#pragma unroll
        for (int t = 0; t < 4; ++t) {
            const int r = r0 + wm * 64 + i * 16 + quad * 4 + t;
            const int L = indices[r];
            const size_t base = (size_t)L * NB, baseZ = (size_t)(L ^ 1) * NB;
#pragma unroll
            for (int j = 0; j < 4; ++j) {
                const int col = b0 + wn * 64 + j * 16 + l15;
                out[base + col] = acc[i][j][t];
                out[baseZ + col] = 0.0f;
            }
        }
}

extern "C" void kernel_launch(void* const* d_in, const int* in_sizes, int n_in,
                              void* d_out, int out_size, void* d_ws, size_t ws_size,
                              hipStream_t stream) {
    const float* weight   = (const float*)d_in[0];
    const int*   indices  = (const int*)d_in[1];
    const int*   metadata = (const int*)d_in[2];
    const float* input    = (const float*)d_in[3];
    float*       out      = (float*)d_out;

    const size_t needA = (size_t)OUT_F * KLOG * 2;  // 32 MB
    const size_t needB = (size_t)NB * KLOG * 2;     // 32 MB
    if (ws_size >= needA + needB) {
        unsigned short* wsA = (unsigned short*)d_ws;
        unsigned short* wsB = wsA + (size_t)OUT_F * KLOG;
        prep_kernel<<<dim3(8192), dim3(256), 0, stream>>>(weight, metadata, input, wsA, wsB);
        gemm_kernel256<<<dim3(256), dim3(512), 0, stream>>>(wsA, wsB, indices, out);
    } else {
        spmm_dt_fallback<<<dim3(NB / 128, OUT_F / 128), dim3(256), 0, stream>>>(
            weight, indices, metadata, input, out);
    }
}

// Round 6
// 354.313 us; speedup vs baseline: 1.0621x; 1.0082x over previous
//
#include <hip/hip_runtime.h>

#define OUT_F 4096   // compressed rows
#define IN_F  2048   // compressed cols
#define KLOG  4096   // logical k = 2*IN_F
#define NB    4096   // batch
typedef unsigned long long ull;
typedef ull ullx2 __attribute__((ext_vector_type(2)));

typedef __bf16 bf16x8 __attribute__((ext_vector_type(8)));
typedef short  s16x8  __attribute__((ext_vector_type(8)));
typedef float  f32x4  __attribute__((ext_vector_type(4)));

__device__ __forceinline__ unsigned short f2bf(float f) {
    unsigned int u = __float_as_uint(f);
    u += 0x7fffu + ((u >> 16) & 1u);
    return (unsigned short)(u >> 16);
}

__device__ __forceinline__ void gload_lds16(const void* g, void* l) {
    __builtin_amdgcn_global_load_lds(
        (const __attribute__((address_space(1))) unsigned int*)g,
        (__attribute__((address_space(3))) unsigned int*)l, 16, 0, 0);
}

__device__ __forceinline__ bf16x8 ldsf(const char* p) {
    return __builtin_bit_cast(bf16x8, *(const s16x8*)p);
}

#define MFMA16(a, b, c) __builtin_amdgcn_mfma_f32_16x16x32_bf16((a), (b), (c), 0, 0, 0)

// ---------- Pre-pass: [0,4096) decompress weight -> bf16 wsA; [4096,8192) input -> bf16 wsB.
__global__ __launch_bounds__(256) void prep_kernel(
    const float* __restrict__ weight, const int* __restrict__ metadata,
    const float* __restrict__ input,
    unsigned short* __restrict__ wsA, unsigned short* __restrict__ wsB)
{
    const int b = blockIdx.x;
    if (b < 4096) {
        const int g = b * 256 + threadIdx.x;
        const int r = g >> 8;
        const int c = (g & 255) * 8;
        const size_t off = (size_t)r * IN_F + c;
        const float4 w0 = *(const float4*)(weight + off);
        const float4 w1 = *(const float4*)(weight + off + 4);
        const int4   m0 = *(const int4*)(metadata + off);
        const int4   m1 = *(const int4*)(metadata + off + 4);
        ullx2 v01, v23;
        v01.x = ((ull)f2bf(w0.x) << (m0.x * 16)) | ((ull)f2bf(w0.y) << (m0.y * 16));
        v01.y = ((ull)f2bf(w0.z) << (m0.z * 16)) | ((ull)f2bf(w0.w) << (m0.w * 16));
        v23.x = ((ull)f2bf(w1.x) << (m1.x * 16)) | ((ull)f2bf(w1.y) << (m1.y * 16));
        v23.y = ((ull)f2bf(w1.z) << (m1.z * 16)) | ((ull)f2bf(w1.w) << (m1.w * 16));
        ull* dst = (ull*)(wsA + (size_t)r * KLOG + 2 * c);
        *(ullx2*)(dst)     = v01;
        *(ullx2*)(dst + 2) = v23;
    } else {
        const int g = (b - 4096) * 256 + threadIdx.x;
        const size_t off = (size_t)g * 16;
        const float4 f0 = *(const float4*)(input + off);
        const float4 f1 = *(const float4*)(input + off + 4);
        const float4 f2 = *(const float4*)(input + off + 8);
        const float4 f3 = *(const float4*)(input + off + 12);
        ullx2 v01, v23;
        v01.x =  (ull)f2bf(f0.x) | ((ull)f2bf(f0.y) << 16) | ((ull)f2bf(f0.z) << 32) | ((ull)f2bf(f0.w) << 48);
        v01.y =  (ull)f2bf(f1.x) | ((ull)f2bf(f1.y) << 16) | ((ull)f2bf(f1.z) << 32) | ((ull)f2bf(f1.w) << 48);
        v23.x =  (ull)f2bf(f2.x) | ((ull)f2bf(f2.y) << 16) | ((ull)f2bf(f2.z) << 32) | ((ull)f2bf(f2.w) << 48);
        v23.y =  (ull)f2bf(f3.x) | ((ull)f2bf(f3.y) << 16) | ((ull)f2bf(f3.z) << 32) | ((ull)f2bf(f3.w) << 48);
        ull* dst = (ull*)(wsB + off);
        *(ullx2*)(dst)     = v01;
        *(ullx2*)(dst + 2) = v23;
    }
}

// ---------- Main GEMM: 256x256 tile, 8 waves (2M x 4N), BK=32, 16x16x32 bf16 MFMA.
// R1 skeleton (ring-4 LDS 128 KB, depth-3 prefetch, counted vmcnt(8), verified staging map)
// with m201's compute shape: 2 phases/tile, 16 MFMA16 per phase, each accumulator touched
// ONCE per tile (16x16x32 covers the whole BK=32 in one instruction) -> matrix pipe drains
// through the next phase's read region; 16x16's low C-reg traffic (4 regs/19cy vs 32x32's
// 16/32cy) frees register-file ports for concurrent ds_read writeback.
// Swizzle: phys 16B-chunk = logical ^ ((row>>1)&3); for 16x16 frags (row = 16*m + l15):
// phys = quad ^ ((l15>>1)&3) -> 8 distinct 16B-slots per 8-lane sweep (conflict-free).
__global__ __launch_bounds__(512, 2) void gemm_kernel256(
    const unsigned short* __restrict__ wsA, const unsigned short* __restrict__ wsB,
    const int* __restrict__ indices, float* __restrict__ out)
{
    __shared__ __align__(16) char lds[4 * 32768];

    const int tid  = threadIdx.x;
    const int lane = tid & 63;
    const int wave = tid >> 6;
    const int wm   = wave >> 2;   // 0..1 : 128-row half of the M-tile
    const int wn   = wave & 3;    // 0..3 : 64-col strip of the N-tile
    const int l15  = lane & 15;
    const int quad = lane >> 4;   // 0..3 : k-chunk of fragment

    const int swz = ((blockIdx.x & 7) << 5) | (blockIdx.x >> 3);
    const int r0 = (swz >> 4) << 8;   // M origin
    const int b0 = (swz & 15) << 8;   // N origin

    // ---- staging (verified map): LDS byte tid*16 -> row tid>>2, phys chunk tid&3;
    //      source logical chunk = phys ^ ((row>>1)&3) ----
    const int srow   = tid >> 2;                      // 0..127
    const int schunk = (tid & 3) ^ ((tid >> 3) & 3);  // pre-swizzled source 16B-chunk
    const unsigned short* gA = wsA + (size_t)(r0 + srow) * KLOG + schunk * 8;
    const unsigned short* gB = wsB + (size_t)(b0 + srow) * KLOG + schunk * 8;
    char* const ldsW = lds + wave * 1024;             // wave-uniform staging base

    // ---- fragment-read constants (16x16x32 pattern) ----
    const unsigned xq    = (unsigned)((quad ^ ((l15 >> 1) & 3)) * 16); // phys 16B offset in 64B row
    const unsigned aBase = (unsigned)((wm * 128 + l15) * 64);          // + rg*1024
    const unsigned bBase = (unsigned)((wn * 64  + l15) * 64);          // + cf*1024

    f32x4 acc[8][4];
#pragma unroll
    for (int i = 0; i < 8; ++i)
#pragma unroll
        for (int j = 0; j < 4; ++j) acc[i][j] = (f32x4){0.f, 0.f, 0.f, 0.f};

#define STAGE_A(t_) do { \
        char* _d = ldsW + (((t_) & 3) * 32768); \
        const unsigned short* _s = gA + (t_) * 32; \
        gload_lds16(_s, _d); \
        gload_lds16(_s + (size_t)128 * KLOG, _d + 8192); } while (0)
#define STAGE_B(t_) do { \
        char* _d = ldsW + (((t_) & 3) * 32768) + 16384; \
        const unsigned short* _s = gB + (t_) * 32; \
        gload_lds16(_s, _d); \
        gload_lds16(_s + (size_t)128 * KLOG, _d + 8192); } while (0)

#define BAR()     __builtin_amdgcn_s_barrier()
#define SCHED0()  __builtin_amdgcn_sched_barrier(0)
#define LGKM0()   asm volatile("s_waitcnt lgkmcnt(0)" ::: "memory")

    // prologue: stage tiles 0,1,2 (12 loads/thread); wait oldest 4 (= tile 0)
    STAGE_A(0); STAGE_B(0);
    STAGE_A(1); STAGE_B(1);
    STAGE_A(2); STAGE_B(2);
    asm volatile("s_waitcnt vmcnt(8)" ::: "memory");
    BAR();
    SCHED0();

    for (int t = 0; t < 128; ++t) {
        const unsigned bufO = (unsigned)(t & 3) * 32768u;
        const char* pA = lds + bufO + aBase;
        const char* pB = lds + bufO + 16384u + bBase;

        // ---------- phase 0: read B0-3 + A0-3 (8 ds_reads), stage A(t+3); MFMA rows 0-3 ----------
        bf16x8 b0f = ldsf(pB + xq);
        bf16x8 b1f = ldsf(pB + 1024 + xq);
        bf16x8 b2f = ldsf(pB + 2048 + xq);
        bf16x8 b3f = ldsf(pB + 3072 + xq);
        bf16x8 a0 = ldsf(pA + xq);
        bf16x8 a1 = ldsf(pA + 1024 + xq);
        bf16x8 a2 = ldsf(pA + 2048 + xq);
        bf16x8 a3 = ldsf(pA + 3072 + xq);
        if (t < 125) STAGE_A(t + 3);
        BAR();
        LGKM0();
        SCHED0();
        __builtin_amdgcn_s_setprio(1);
        acc[0][0] = MFMA16(a0, b0f, acc[0][0]);
        acc[0][1] = MFMA16(a0, b1f, acc[0][1]);
        acc[0][2] = MFMA16(a0, b2f, acc[0][2]);
        acc[0][3] = MFMA16(a0, b3f, acc[0][3]);
        acc[1][0] = MFMA16(a1, b0f, acc[1][0]);
        acc[1][1] = MFMA16(a1, b1f, acc[1][1]);
        acc[1][2] = MFMA16(a1, b2f, acc[1][2]);
        acc[1][3] = MFMA16(a1, b3f, acc[1][3]);
        acc[2][0] = MFMA16(a2, b0f, acc[2][0]);
        acc[2][1] = MFMA16(a2, b1f, acc[2][1]);
        acc[2][2] = MFMA16(a2, b2f, acc[2][2]);
        acc[2][3] = MFMA16(a2, b3f, acc[2][3]);
        acc[3][0] = MFMA16(a3, b0f, acc[3][0]);
        acc[3][1] = MFMA16(a3, b1f, acc[3][1]);
        acc[3][2] = MFMA16(a3, b2f, acc[3][2]);
        acc[3][3] = MFMA16(a3, b3f, acc[3][3]);
        __builtin_amdgcn_s_setprio(0);
        BAR();
        SCHED0();

        // ---------- phase 1: read A4-7 (4 ds_reads), stage B(t+3); MFMA rows 4-7 ----------
        bf16x8 a4 = ldsf(pA + 4096 + xq);
        bf16x8 a5 = ldsf(pA + 5120 + xq);
        bf16x8 a6 = ldsf(pA + 6144 + xq);
        bf16x8 a7 = ldsf(pA + 7168 + xq);
        if (t < 125) STAGE_B(t + 3);
        BAR();
        LGKM0();
        SCHED0();
        __builtin_amdgcn_s_setprio(1);
        acc[4][0] = MFMA16(a4, b0f, acc[4][0]);
        acc[4][1] = MFMA16(a4, b1f, acc[4][1]);
        acc[4][2] = MFMA16(a4, b2f, acc[4][2]);
        acc[4][3] = MFMA16(a4, b3f, acc[4][3]);
        acc[5][0] = MFMA16(a5, b0f, acc[5][0]);
        acc[5][1] = MFMA16(a5, b1f, acc[5][1]);
        acc[5][2] = MFMA16(a5, b2f, acc[5][2]);
        acc[5][3] = MFMA16(a5, b3f, acc[5][3]);
        acc[6][0] = MFMA16(a6, b0f, acc[6][0]);
        acc[6][1] = MFMA16(a6, b1f, acc[6][1]);
        acc[6][2] = MFMA16(a6, b2f, acc[6][2]);
        acc[6][3] = MFMA16(a6, b3f, acc[6][3]);
        acc[7][0] = MFMA16(a7, b0f, acc[7][0]);
        acc[7][1] = MFMA16(a7, b1f, acc[7][1]);
        acc[7][2] = MFMA16(a7, b2f, acc[7][2]);
        acc[7][3] = MFMA16(a7, b3f, acc[7][3]);
        __builtin_amdgcn_s_setprio(0);

        // ---- tile end: counted vmcnt (never 0 until tail) + the tile boundary barrier ----
        if (t < 125) {
            asm volatile("s_waitcnt vmcnt(8)" ::: "memory");   // tile t+1 landed; t+2,t+3 in flight
        } else if (t == 125) {
            asm volatile("s_waitcnt vmcnt(4)" ::: "memory");   // tile 126 landed; 127 in flight
        } else if (t == 126) {
            asm volatile("s_waitcnt vmcnt(0)" ::: "memory");   // tile 127 landed
        }
        BAR();
        SCHED0();
    }
#undef STAGE_A
#undef STAGE_B
#undef BAR
#undef SCHED0
#undef LGKM0

    // epilogue: C/D (16x16): col = l15, row = quad*4 + e  [verified fallback layout]
#pragma unroll
    for (int rg = 0; rg < 8; ++rg) {
#pragma unroll
        for (int e = 0; e < 4; ++e) {
            const int rloc = wm * 128 + rg * 16 + quad * 4 + e;
            const int L = indices[r0 + rloc];
            const size_t base  = (size_t)L * NB;
            const size_t baseZ = (size_t)(L ^ 1) * NB;
#pragma unroll
            for (int cf = 0; cf < 4; ++cf) {
                const int col = b0 + wn * 64 + cf * 16 + l15;
                out[base  + col] = acc[rg][cf][e];
                out[baseZ + col] = 0.0f;
            }
        }
    }
}

// ---------- Fallback (round-1 fused kernel) if ws is too small ----------
__global__ __launch_bounds__(256) void spmm_dt_fallback(
    const float* __restrict__ weight, const int* __restrict__ indices,
    const int* __restrict__ metadata, const float* __restrict__ input,
    float* __restrict__ out)
{
    __shared__ __align__(16) unsigned short As[128][32];
    __shared__ __align__(16) unsigned short Bs[128][32];
    const int tid = threadIdx.x, lane = tid & 63, wave = tid >> 6;
    const int wm = wave >> 1, wn = wave & 1, l15 = lane & 15, quad = lane >> 4;
    const int r0 = blockIdx.y * 128, b0 = blockIdx.x * 128;
    f32x4 acc[4][4];
#pragma unroll
    for (int i = 0; i < 4; ++i)
#pragma unroll
        for (int j = 0; j < 4; ++j) acc[i][j] = (f32x4){0.f, 0.f, 0.f, 0.f};
    const int srow = tid >> 3, sgrp = tid & 7;
    for (int kk = 0; kk < KLOG / 32; ++kk) {
        const int c0 = kk * 16, k0 = kk * 32;
#pragma unroll
        for (int s = 0; s < 4; ++s) {
            const int row = srow + s * 32;
            const size_t off = (size_t)(r0 + row) * IN_F + c0 + 2 * sgrp;
            const float2 w = *(const float2*)(weight + off);
            const int2  md = *(const int2*)(metadata + off);
            *(ull*)(&As[row][4 * sgrp]) =
                ((ull)f2bf(w.x) << (md.x * 16)) | ((ull)f2bf(w.y) << (md.y * 16));
        }
#pragma unroll
        for (int s = 0; s < 4; ++s) {
            const int row = srow + s * 32;
            const float4 f = *(const float4*)(&input[(size_t)(b0 + row) * KLOG + k0 + sgrp * 4]);
            *(ull*)(&Bs[row][sgrp * 4]) =
                 (ull)f2bf(f.x) | ((ull)f2bf(f.y) << 16) |
                ((ull)f2bf(f.z) << 32) | ((ull)f2bf(f.w) << 48);
        }
        __syncthreads();
        bf16x8 a[4], b[4];
#pragma unroll
        for (int i = 0; i < 4; ++i)
            a[i] = __builtin_bit_cast(bf16x8, *(const s16x8*)(&As[wm * 64 + i * 16 + l15][quad * 8]));
#pragma unroll
        for (int j = 0; j < 4; ++j)
            b[j] = __builtin_bit_cast(bf16x8, *(const s16x8*)(&Bs[wn * 64 + j * 16 + l15][quad * 8]));
#pragma unroll
        for (int i = 0; i < 4; ++i)
#pragma unroll
            for (int j = 0; j < 4; ++j)
                acc[i][j] = __builtin_amdgcn_mfma_f32_16x16x32_bf16(a[i], b[j], acc[i][j], 0, 0, 0);
        __syncthreads();
    }
#pragma unroll
    for (int i = 0; i < 4; ++i)
#pragma unroll
        for (int t = 0; t < 4; ++t) {
            const int r = r0 + wm * 64 + i * 16 + quad * 4 + t;
            const int L = indices[r];
            const size_t base = (size_t)L * NB, baseZ = (size_t)(L ^ 1) * NB;
#pragma unroll
            for (int j = 0; j < 4; ++j) {
                const int col = b0 + wn * 64 + j * 16 + l15;
                out[base + col] = acc[i][j][t];
                out[baseZ + col] = 0.0f;
            }
        }
}

extern "C" void kernel_launch(void* const* d_in, const int* in_sizes, int n_in,
                              void* d_out, int out_size, void* d_ws, size_t ws_size,
                              hipStream_t stream) {
    const float* weight   = (const float*)d_in[0];
    const int*   indices  = (const int*)d_in[1];
    const int*   metadata = (const int*)d_in[2];
    const float* input    = (const float*)d_in[3];
    float*       out      = (float*)d_out;

    const size_t needA = (size_t)OUT_F * KLOG * 2;  // 32 MB
    const size_t needB = (size_t)NB * KLOG * 2;     // 32 MB
    if (ws_size >= needA + needB) {
        unsigned short* wsA = (unsigned short*)d_ws;
        unsigned short* wsB = wsA + (size_t)OUT_F * KLOG;
        prep_kernel<<<dim3(8192), dim3(256), 0, stream>>>(weight, metadata, input, wsA, wsB);
        gemm_kernel256<<<dim3(256), dim3(512), 0, stream>>>(wsA, wsB, indices, out);
    } else {
        spmm_dt_fallback<<<dim3(NB / 128, OUT_F / 128), dim3(256), 0, stream>>>(
            weight, indices, metadata, input, out);
    }
}